// Round 8
// baseline (298.255 us; speedup 1.0000x reference)
//
#include <hip/hip_runtime.h>
#include <math.h>

typedef float f32x4 __attribute__((ext_vector_type(4)));

// ---------------------------------------------------------------------------
// Prep (256 blocks x 256 thr): per node i, feature f:
//   Wh  = h @ W                         (K=128 dot)
//   s1  = adj @ a[:64], s2 = adj @ a[64:]
//   EA1 = exp(s1), EA2 = exp(0.2*s1)
//   EB1 = adj[i,f]>0 ? exp(s2) : 0, EB2 = adj[i,f]>0 ? exp(0.2*s2) : 0
// Identity: exp(leakyrelu(s1+s2)) = max(EA1*EB1, EA2*EB2); mask -> exact 0.
// ---------------------------------------------------------------------------
__global__ __launch_bounds__(256) void gat_prep(
    const float* __restrict__ h, const float* __restrict__ adj,
    const float* __restrict__ W, const float* __restrict__ a,
    float* __restrict__ Wh, float* __restrict__ EA1, float* __restrict__ EA2,
    float* __restrict__ EB1, float* __restrict__ EB2)
{
    const int t = threadIdx.x;
    const int f = t & 63;
    const int i = (blockIdx.x << 2) + (t >> 6);   // wave-uniform row

    const float* __restrict__ hrow = h + i * 128;
    const float* __restrict__ arow = adj + i * 64;

    float wh = 0.0f;
    #pragma unroll 8
    for (int k = 0; k < 128; ++k) wh = fmaf(hrow[k], W[k * 64 + f], wh);
    Wh[i * 64 + f] = wh;

    float v1 = 0.0f, v2 = 0.0f;
    #pragma unroll 8
    for (int k = 0; k < 64; ++k) {
        const float av = arow[k];
        v1 = fmaf(av, a[k * 64 + f], v1);
        v2 = fmaf(av, a[(64 + k) * 64 + f], v2);
    }
    EA1[i * 64 + f] = __expf(v1);
    EA2[i * 64 + f] = __expf(0.2f * v1);
    const bool m = arow[f] > 0.0f;                // source-node mask adj[j,f]>0
    EB1[i * 64 + f] = m ? __expf(v2) : 0.0f;
    EB2[i * 64 + f] = m ? __expf(0.2f * v2) : 0.0f;
}

// ---------------------------------------------------------------------------
// Z + h_prime (1024 blocks x 256 thr, one row i per block). NO att stores
// happen while this runs -> EB1/EB2/Wh (768KB) stay L2-resident; ~786MB of
// L2-hit reads, ~25us. Key algebra: h_prime = zinv * sum_j e*Wh, so h_prime
// is finished BEFORE the 268MB att store sweep begins.
// ---------------------------------------------------------------------------
__global__ __launch_bounds__(256) void gat_zh(
    const float* __restrict__ EA1, const float* __restrict__ EA2,
    const float* __restrict__ EB1, const float* __restrict__ EB2,
    const float* __restrict__ Wh,
    float* __restrict__ zinv_g, float* __restrict__ out_hp)
{
    __shared__ float redz[16][64];
    __shared__ float redh[16][64];

    const int t  = threadIdx.x;
    const int fg = t & 15;
    const int jo = t >> 4;          // 0..15
    const int fb = fg << 2;
    const int i  = blockIdx.x;

    const f32x4 a1 = *reinterpret_cast<const f32x4*>(EA1 + i * 64 + fb);
    const f32x4 a2 = *reinterpret_cast<const f32x4*>(EA2 + i * 64 + fb);

    f32x4 z  = {0.f, 0.f, 0.f, 0.f};
    f32x4 hv = {0.f, 0.f, 0.f, 0.f};
    #pragma unroll 4
    for (int jb = 0; jb < 1024; jb += 16) {
        const int j = jb + jo;
        const f32x4 b1 = *reinterpret_cast<const f32x4*>(EB1 + j * 64 + fb);
        const f32x4 b2 = *reinterpret_cast<const f32x4*>(EB2 + j * 64 + fb);
        const f32x4 wv = *reinterpret_cast<const f32x4*>(Wh  + j * 64 + fb);
        f32x4 e;
        e.x = fmaxf(a1.x * b1.x, a2.x * b2.x);
        e.y = fmaxf(a1.y * b1.y, a2.y * b2.y);
        e.z = fmaxf(a1.z * b1.z, a2.z * b2.z);
        e.w = fmaxf(a1.w * b1.w, a2.w * b2.w);
        z.x += e.x; z.y += e.y; z.z += e.z; z.w += e.w;
        hv.x = fmaf(e.x, wv.x, hv.x);
        hv.y = fmaf(e.y, wv.y, hv.y);
        hv.z = fmaf(e.z, wv.z, hv.z);
        hv.w = fmaf(e.w, wv.w, hv.w);
    }
    *reinterpret_cast<f32x4*>(&redz[jo][fb]) = z;
    *reinterpret_cast<f32x4*>(&redh[jo][fb]) = hv;
    __syncthreads();
    if (t < 64) {
        float zs = 0.0f, hs = 0.0f;
        #pragma unroll
        for (int o = 0; o < 16; ++o) { zs += redz[o][t]; hs += redh[o][t]; }
        const float iv = 1.0f / zs;
        zinv_g[i * 64 + t] = iv;
        const float v = hs * iv;
        out_hp[i * 64 + t] = (v > 0.0f) ? v : expm1f(v);
    }
}

// ---------------------------------------------------------------------------
// att writer (256 blocks x 1024 thr): TI=4 rows per block -> EB1/EB2 read
// traffic is 8B/elem/4rows = 128MB total. No LDS, no barriers. Depth-2
// pipeline: prefetch loads issued before this step's stores so load-use
// vmcnt waits never queue behind the HBM store drain. Plain f32x4 stores
// (fills prove plain stores reach 6.3 TB/s; NT measured neutral/negative).
// jo = t>>4 in 0..63, fg = t&15: per row a wave covers 4 j x 256B = 1KiB
// contiguous; block iteration covers 16KiB contiguous per row.
// ---------------------------------------------------------------------------
__global__ __launch_bounds__(1024) void gat_att(
    const float* __restrict__ EA1, const float* __restrict__ EA2,
    const float* __restrict__ EB1, const float* __restrict__ EB2,
    const float* __restrict__ zinv_g,
    float* __restrict__ out_att)
{
    const int t  = threadIdx.x;
    const int fg = t & 15;
    const int jo = t >> 4;          // 0..63
    const int fb = fg << 2;
    const int i0 = blockIdx.x << 2;

    f32x4 s1[4], s2[4];             // folded EA*zinv per row (unroll -> regs)
    #pragma unroll
    for (int r = 0; r < 4; ++r) {
        const f32x4 a1 = *reinterpret_cast<const f32x4*>(EA1 + (i0 + r) * 64 + fb);
        const f32x4 a2 = *reinterpret_cast<const f32x4*>(EA2 + (i0 + r) * 64 + fb);
        const f32x4 iv = *reinterpret_cast<const f32x4*>(zinv_g + (i0 + r) * 64 + fb);
        s1[r].x = a1.x * iv.x; s1[r].y = a1.y * iv.y; s1[r].z = a1.z * iv.z; s1[r].w = a1.w * iv.w;
        s2[r].x = a2.x * iv.x; s2[r].y = a2.y * iv.y; s2[r].z = a2.z * iv.z; s2[r].w = a2.w * iv.w;
    }

    const int jbase = jo * 64 + fb;
    float* __restrict__ o0 = out_att + (size_t)i0 * 65536 + fb;

    // prologue: bank A <- j-block 0, bank B <- j-block 64
    f32x4 b1A = *reinterpret_cast<const f32x4*>(EB1 + jbase);
    f32x4 b2A = *reinterpret_cast<const f32x4*>(EB2 + jbase);
    f32x4 b1B = *reinterpret_cast<const f32x4*>(EB1 + jbase + 64 * 64);
    f32x4 b2B = *reinterpret_cast<const f32x4*>(EB2 + jbase + 64 * 64);

    for (int jb = 0; jb < 1024; jb += 128) {
        // ---- half-step A: consumes jb, prefetches jb+128 ----
        {
            f32x4 o_[4];
            #pragma unroll
            for (int r = 0; r < 4; ++r) {
                o_[r].x = fmaxf(s1[r].x * b1A.x, s2[r].x * b2A.x);
                o_[r].y = fmaxf(s1[r].y * b1A.y, s2[r].y * b2A.y);
                o_[r].z = fmaxf(s1[r].z * b1A.z, s2[r].z * b2A.z);
                o_[r].w = fmaxf(s1[r].w * b1A.w, s2[r].w * b2A.w);
            }
            const int jp = (jb + 128) & 1023;     // wraps on last iter (dummy)
            b1A = *reinterpret_cast<const f32x4*>(EB1 + jp * 64 + jbase);
            b2A = *reinterpret_cast<const f32x4*>(EB2 + jp * 64 + jbase);
            #pragma unroll
            for (int r = 0; r < 4; ++r)
                *reinterpret_cast<f32x4*>(o0 + r * 65536 + jb * 64 + jo * 64) = o_[r];
        }
        // ---- half-step B: consumes jb+64, prefetches jb+192 ----
        {
            f32x4 o_[4];
            #pragma unroll
            for (int r = 0; r < 4; ++r) {
                o_[r].x = fmaxf(s1[r].x * b1B.x, s2[r].x * b2B.x);
                o_[r].y = fmaxf(s1[r].y * b1B.y, s2[r].y * b2B.y);
                o_[r].z = fmaxf(s1[r].z * b1B.z, s2[r].z * b2B.z);
                o_[r].w = fmaxf(s1[r].w * b1B.w, s2[r].w * b2B.w);
            }
            const int jp = (jb + 192) & 1023;
            b1B = *reinterpret_cast<const f32x4*>(EB1 + jp * 64 + jbase);
            b2B = *reinterpret_cast<const f32x4*>(EB2 + jp * 64 + jbase);
            #pragma unroll
            for (int r = 0; r < 4; ++r)
                *reinterpret_cast<f32x4*>(o0 + r * 65536 + (jb + 64) * 64 + jo * 64) = o_[r];
        }
    }
}

extern "C" void kernel_launch(void* const* d_in, const int* in_sizes, int n_in,
                              void* d_out, int out_size, void* d_ws, size_t ws_size,
                              hipStream_t stream) {
    const float* h   = (const float*)d_in[0];   // (1024, 128)
    const float* adj = (const float*)d_in[1];   // (1024, 64)
    const float* W   = (const float*)d_in[2];   // (128, 64)
    const float* a   = (const float*)d_in[3];   // (128, 64)

    float* ws   = (float*)d_ws;                 // 1.5 MiB scratch used
    float* Wh   = ws;                           // (1024, 64)
    float* EA1  = ws + 65536;
    float* EA2  = ws + 131072;
    float* EB1  = ws + 196608;
    float* EB2  = ws + 262144;
    float* zinv = ws + 327680;

    float* out     = (float*)d_out;
    float* out_hp  = out;                       // elu(h_prime): 65536 floats
    float* out_att = out + 65536;               // attention: 1024*1024*64

    gat_prep<<<256, 256, 0, stream>>>(h, adj, W, a, Wh, EA1, EA2, EB1, EB2);
    gat_zh<<<1024, 256, 0, stream>>>(EA1, EA2, EB1, EB2, Wh, zinv, out_hp);
    gat_att<<<256, 1024, 0, stream>>>(EA1, EA2, EB1, EB2, zinv, out_att);
}